// Round 7
// baseline (258.652 us; speedup 1.0000x reference)
//
#include <hip/hip_runtime.h>

typedef __bf16 bf16x8 __attribute__((ext_vector_type(8)));
typedef __bf16 bf16x4 __attribute__((ext_vector_type(4)));
typedef float f32x4 __attribute__((ext_vector_type(4)));

#define EPS_F 1e-5f

// -------------------------------------------------------------------------
// Kernel 1 (MFMA): pooled_part[mc][b][r-slice] partial pool of hswish(BN(x@w1))
// Round 12: kill k_pack. Reg-staged fused transpose (R2 dataflow) under the
// R6 schedule (raw s_barrier, compiler-COUNTED vmcnt — no __syncthreads
// drain): A fp32 global->reg issued 1 step ahead -> cvt/transpose ->
// ds_write to dbuf; B (w1, L2-resident) global->reg 1 step ahead, cvt to
// frags, never touches LDS. ONE barrier per K-step. Saves: pack launch+gap,
// 103 MB xt HBM round-trip.
// grid 512 (b, mc, nh): block 512 (8 waves 2m x 4n), M=112 x N=128 x K=1024.
// LDS 19 KB; __launch_bounds__(512,4) caps VGPR 128 -> 2 blocks/CU so one
// block's barrier bubbles are filled by the other.
// -------------------------------------------------------------------------
__global__ __launch_bounds__(512, 4) void k_gemm_pool(
    const float* __restrict__ x,
    const float* __restrict__ w1,
    const float* __restrict__ g1,
    const float* __restrict__ b1,
    const float* __restrict__ m1,
    const float* __restrict__ v1,
    float* __restrict__ pooled_part)     // [2][128][256]
{
    constexpr int LDK = 40;              // padded k-stride (bf16), R0-proven
    __shared__ __bf16 Alds[2][112 * LDK];  // 17.9 KiB
    __shared__ float pool_lds[2][128];

    const int bid = blockIdx.x;
    const int b   = bid & 127;
    const int mc  = (bid >> 7) & 1;          // m-chunk: p in [mc*112, ...)
    const int nh  = bid >> 8;                // n-half: r in [nh*128, ...)
    const int tid = threadIdx.x;
    const int wave = tid >> 6, lane = tid & 63;
    const int wm = wave >> 2, wn = wave & 3;   // wave grid 2(m) x 4(n)
    const int q  = lane >> 4, ln = lane & 15;
    const int nm = (wm == 0) ? 4 : 3;          // 7 m-tiles split 4 + 3

    f32x4 acc[4][2];
#pragma unroll
    for (int i = 0; i < 4; i++)
#pragma unroll
        for (int j = 0; j < 2; j++) acc[i][j] = (f32x4){0.f, 0.f, 0.f, 0.f};

    // ---- A staging: unit = 4c x 4p, 224 active threads ----
    const int c4  = tid & 7;                 // c-group (4 channels)
    const int p4  = tid >> 3;                // p-group (4 positions), active < 28
    const bool a_act = (p4 < 28);
    const int  pg    = mc * 28 + p4;
    const bool a_val = a_act && (pg < 49);   // p>=196 -> zero rows
    const float* xb = x + (size_t)b * (1024 * 196) + pg * 4;

    float fA[4][4];                          // [c][p] fp32 staging regs
    auto loadA = [&](int kc) {
        if (a_val) {
#pragma unroll
            for (int i = 0; i < 4; i++) {
                const float4 f = *(const float4*)(xb + (size_t)(kc + c4 * 4 + i) * 196);
                fA[i][0] = f.x; fA[i][1] = f.y; fA[i][2] = f.z; fA[i][3] = f.w;
            }
        } else {
#pragma unroll
            for (int i = 0; i < 4; i++)
#pragma unroll
                for (int j = 0; j < 4; j++) fA[i][j] = 0.f;
        }
    };
    auto storeA = [&](int buf) {
        if (a_act) {
#pragma unroll
            for (int j = 0; j < 4; j++) {
                bf16x4 o = {(__bf16)fA[0][j], (__bf16)fA[1][j],
                            (__bf16)fA[2][j], (__bf16)fA[3][j]};
                *(bf16x4*)&Alds[buf][(p4 * 4 + j) * LDK + c4 * 4] = o;
            }
        }
    };

    // ---- B: per-wave direct global (row = nh*128 + (wn*2+ni)*16 + ln) ----
    const float* wBr = w1 + (size_t)(nh * 128 + wn * 32 + ln) * 1024 + q * 8;
    float4 fB[2][2];
    auto loadB = [&](int kc) {
#pragma unroll
        for (int ni = 0; ni < 2; ni++) {
            fB[ni][0] = *(const float4*)(wBr + ni * 16384 + kc);
            fB[ni][1] = *(const float4*)(wBr + ni * 16384 + kc + 4);
        }
    };

    // ---- prologue: buf0 ready, A(1)/B(0) in flight ----
    loadA(0);
    storeA(0);                               // compiler inserts counted vmcnt
    loadA(32);
    loadB(0);
    asm volatile("s_waitcnt lgkmcnt(0)" ::: "memory");
    __builtin_amdgcn_s_barrier();

    for (int t = 0; t < 32; ++t) {
        const int kc = t * 32;
        // B(t): cvt regs -> frags (counted vmcnt wait), prefetch B(t+1)
        bf16x8 bfr[2];
#pragma unroll
        for (int ni = 0; ni < 2; ni++)
            bfr[ni] = (bf16x8){(__bf16)fB[ni][0].x, (__bf16)fB[ni][0].y,
                               (__bf16)fB[ni][0].z, (__bf16)fB[ni][0].w,
                               (__bf16)fB[ni][1].x, (__bf16)fB[ni][1].y,
                               (__bf16)fB[ni][1].z, (__bf16)fB[ni][1].w};
        if (t < 31) loadB(kc + 32);
        // MFMA on Alds[t&1]
#pragma unroll
        for (int mi = 0; mi < 4; mi++) {
            if (mi < nm) {
                const bf16x8 af =
                    *(const bf16x8*)&Alds[t & 1][((wm * 4 + mi) * 16 + ln) * LDK + q * 8];
#pragma unroll
                for (int ni = 0; ni < 2; ni++)
                    acc[mi][ni] = __builtin_amdgcn_mfma_f32_16x16x32_bf16(
                        af, bfr[ni], acc[mi][ni], 0, 0, 0);
            }
        }
        // stage A(t+1) into the other buffer; prefetch A(t+2)
        if (t < 31) {
            storeA((t + 1) & 1);             // counted vmcnt wait on fA
            if (t < 30) loadA(kc + 64);
        }
        asm volatile("s_waitcnt lgkmcnt(0)" ::: "memory");
        __builtin_amdgcn_sched_barrier(0);
        __builtin_amdgcn_s_barrier();        // step t reads done; buf swap safe
        __builtin_amdgcn_sched_barrier(0);
    }

    // ---- epilogue: BN + hardswish + partial pool (mask p >= 196) ----
    float psum[2] = {0.f, 0.f};
#pragma unroll
    for (int ni = 0; ni < 2; ni++) {
        const int r = nh * 128 + (wn * 2 + ni) * 16 + ln;
        const float s1 = g1[r] * rsqrtf(v1[r] + EPS_F);
        const float mu = m1[r];
        const float be = b1[r];
#pragma unroll
        for (int mi = 0; mi < 4; mi++) {
            if (mi < nm) {
#pragma unroll
                for (int i = 0; i < 4; i++) {
                    const int m = mc * 112 + (wm * 4 + mi) * 16 + q * 4 + i;
                    if (m < 196) {
                        float v = acc[mi][ni][i];
                        v = (v - mu) * s1 + be;
                        const float g = fminf(fmaxf(v + 3.f, 0.f), 6.f);
                        psum[ni] += v * g * (1.f / 6.f);
                    }
                }
            }
        }
    }
#pragma unroll
    for (int ni = 0; ni < 2; ni++) {
        psum[ni] += __shfl_xor(psum[ni], 16, 64);
        psum[ni] += __shfl_xor(psum[ni], 32, 64);
    }
    if (lane < 16) {
#pragma unroll
        for (int ni = 0; ni < 2; ni++)
            pool_lds[wm][(wn * 2 + ni) * 16 + lane] = psum[ni];
    }
    __syncthreads();
    if (tid < 128)
        pooled_part[(size_t)mc * (128 * 256) + b * 256 + nh * 128 + tid] =
            (pool_lds[0][tid] + pool_lds[1][tid]) * (1.f / 196.f);
}

__device__ __forceinline__ void prep1(float s, float e, int n, int size, int i,
                                      int& lo, int& hi, float& w0, float& w1)
{
    const float bsz = (e - s) / (float)n;
    float c = s + ((float)i + 0.5f) * bsz;
    const float valid = (c >= -1.f && c <= (float)size) ? 1.f : 0.f;
    c = fminf(fmaxf(c, 0.f), (float)(size - 1));
    lo = (int)floorf(c);
    hi = min(lo + 1, size - 1);
    const float f = c - (float)lo;
    w0 = (1.f - f) * valid;
    w1 = f * valid;
}

// -------------------------------------------------------------------------
// Kernel 3 (fused logits+ROI): each block first computes the 6 roi params
// from pooled_part (64 threads, hidden under the x-staging loads), then
// ROI-align. grid (128, 32), block 256.
// -------------------------------------------------------------------------
__global__ __launch_bounds__(256) void k_roi(
    const float* __restrict__ x,
    const float* __restrict__ pooled_part,   // [2][128][256]
    const float* __restrict__ w2,
    const float* __restrict__ g2,
    const float* __restrict__ b2,
    const float* __restrict__ m2,
    const float* __restrict__ v2,
    float* __restrict__ out)
{
    __shared__ float xs[32 * 200];   // 32 ch x 196 (pad 200)  25.6 KiB
    __shared__ int   soff[8][80];    // sample flat offsets (po-major)
    __shared__ float swt[8][80];     // sample weights
    __shared__ float roi_s[6];

    const int b = blockIdx.x, c0 = blockIdx.y * 32;
    const int tid = threadIdx.x;

    // ---- stage 32 channels, coalesced float4 (196 = 49*4) ----
    const float* xb = x + ((size_t)b * 1024 + c0) * 196;
#pragma unroll
    for (int k = 0; k < 7; k++) {
        const int i4 = tid + k * 256;
        if (i4 < 1568) {                       // 32*49
            const int c = i4 / 49, pq = i4 % 49;
            const float4 v = *(const float4*)(xb + c * 196 + pq * 4);
            *(float4*)&xs[c * 200 + pq * 4] = v;
        }
    }
    // ---- logits (wave 0), overlapped with staging ----
    if (tid < 64) {
        const float4 pa = ((const float4*)(pooled_part + b * 256))[tid];
        const float4 pb = ((const float4*)(pooled_part + 128 * 256 + b * 256))[tid];
        float4 p4;
        p4.x = pa.x + pb.x; p4.y = pa.y + pb.y;
        p4.z = pa.z + pb.z; p4.w = pa.w + pb.w;
        float part[6];
#pragma unroll
        for (int j = 0; j < 6; j++) {
            const float4 w = *(const float4*)(w2 + j * 256 + tid * 4);
            part[j] = p4.x * w.x + p4.y * w.y + p4.z * w.z + p4.w * w.w;
        }
#pragma unroll
        for (int j = 0; j < 6; j++)
#pragma unroll
            for (int off = 32; off >= 1; off >>= 1)
                part[j] += __shfl_xor(part[j], off, 64);
        if (tid == 0) {
            const float SC[3] = {7.f, 7.f, 4.f};
#pragma unroll
            for (int j = 0; j < 6; j++) {
                float l = part[j];
                const float s = g2[j] * rsqrtf(v2[j] + EPS_F);
                l = (l - m2[j]) * s + b2[j];
                const float raw = 1.f / (1.f + expf(-l));
                roi_s[j] = (j < 3) ? 0.5f * raw * SC[j]
                                   : (1.f - 0.5f * raw) * SC[j - 3];
            }
        }
    }
    __syncthreads();
    // ---- weight/offset tables (75 threads) ----
    if (tid < 75) {
        const int po = tid;
        const int to = po / 25, rem = po % 25, yo = rem / 5, xo = rem % 5;
        int tl, th, yl, yh, xl, xh;
        float tw0, tw1, yw0, yw1, xw0, xw1;
        prep1(roi_s[2], roi_s[5], 3, 4, to, tl, th, tw0, tw1);
        prep1(roi_s[1], roi_s[4], 5, 7, yo, yl, yh, yw0, yw1);
        prep1(roi_s[0], roi_s[3], 5, 7, xo, xl, xh, xw0, xw1);
#pragma unroll
        for (int s = 0; s < 8; s++) {
            const int   ti = (s & 4) ? th : tl;
            const int   yi = (s & 2) ? yh : yl;
            const int   xi = (s & 1) ? xh : xl;
            const float w = ((s & 4) ? tw1 : tw0) *
                            ((s & 2) ? yw1 : yw0) *
                            ((s & 1) ? xw1 : xw0);
            soff[s][po] = ti * 49 + yi * 7 + xi;
            swt[s][po]  = w;
        }
    }
    __syncthreads();

    // ---- compute: 32*75 = 2400 outputs ----
    const size_t obase = ((size_t)b * 1024 + c0) * 75;
#pragma unroll
    for (int k = 0; k < 10; k++) {
        const int e = tid + k * 256;
        if (e < 2400) {
            const int c = e / 75, po = e % 75;
            const float* row = &xs[c * 200];
            float v = 0.f;
#pragma unroll
            for (int s = 0; s < 8; s++)
                v += swt[s][po] * row[soff[s][po]];
            out[obase + e] = v;     // e == c*75+po: fully coalesced
        }
    }
}

extern "C" void kernel_launch(void* const* d_in, const int* in_sizes, int n_in,
                              void* d_out, int out_size, void* d_ws, size_t ws_size,
                              hipStream_t stream)
{
    const float* x  = (const float*)d_in[0];
    const float* w1 = (const float*)d_in[1];
    const float* g1 = (const float*)d_in[2];
    const float* b1 = (const float*)d_in[3];
    const float* m1 = (const float*)d_in[4];
    const float* v1 = (const float*)d_in[5];
    const float* w2 = (const float*)d_in[6];
    const float* g2 = (const float*)d_in[7];
    const float* b2 = (const float*)d_in[8];
    const float* m2 = (const float*)d_in[9];
    const float* v2 = (const float*)d_in[10];

    float* pooled = (float*)d_ws;            // 2*128*256 f32
    float* out    = (float*)d_out;

    k_gemm_pool<<<512, 512, 0, stream>>>(x, w1, g1, b1, m1, v1, pooled);
    k_roi<<<dim3(128, 32), 256, 0, stream>>>(x, pooled, w2, g2, b2, m2, v2, out);
}